// Round 2
// baseline (3981.432 us; speedup 1.0000x reference)
//
#include <hip/hip_runtime.h>
#include <hip/hip_bf16.h>

typedef short bf16v8 __attribute__((ext_vector_type(8)));
typedef float f32x4 __attribute__((ext_vector_type(4)));

// B=128, T=32, E=512, H=512, L=256, V=16000
// out: p_mu[4096x256], p_sig, q_mu, q_sig, q_x[4096x16000]

__device__ __forceinline__ void gload16(const void* g, void* l) {
    __builtin_amdgcn_global_load_lds(
        (const __attribute__((address_space(1))) void*)g,
        (__attribute__((address_space(3))) void*)l,
        16, 0, 0);
}

__device__ __forceinline__ float sigm(float x) { return 1.f / (1.f + __expf(-x)); }

// ---------- generic bf16 MFMA GEMM: C[M][N] = A[M][K]*B[N][K]^T (+bias) ----------
// 128x128 tile, BK=32, 4 waves 2x2, wave 64x64 = 4x4 frags of 16x16x32.
// nMax: early-return guard so grid can be padded for XCD-L2 locality.
template<int SPLIT>
__global__ __launch_bounds__(256, 2) void gemm_bt(
    const __hip_bfloat16* __restrict__ A, int ldA,
    const __hip_bfloat16* __restrict__ B, int ldB,
    float* __restrict__ C, int ldC, float* __restrict__ C2,
    const float* __restrict__ bias,
    int K, int nTilesN, int nMax)
{
    __shared__ __hip_bfloat16 As[128 * 32];
    __shared__ __hip_bfloat16 Bs[128 * 32];
    const int bid = blockIdx.x;
    const int bm = bid / nTilesN, bn = bid % nTilesN;
    const int m0 = bm * 128, n0 = bn * 128;
    if (n0 >= nMax) return;
    const int tid = threadIdx.x, lane = tid & 63, wave = tid >> 6;
    const int wm = (wave & 1) * 64, wn = (wave >> 1) * 64;
    f32x4 acc[4][4] = {};

    const int ci0 = wave, ci1 = wave + 4;
    const int srow0 = ci0 * 16 + (lane >> 2);
    const int srow1 = ci1 * 16 + (lane >> 2);
    const int scol = (lane & 3) * 8;
    const __hip_bfloat16* Ag0 = A + (size_t)(m0 + srow0) * ldA + scol;
    const __hip_bfloat16* Ag1 = A + (size_t)(m0 + srow1) * ldA + scol;
    const __hip_bfloat16* Bg0 = B + (size_t)(n0 + srow0) * ldB + scol;
    const __hip_bfloat16* Bg1 = B + (size_t)(n0 + srow1) * ldB + scol;
    char* AsB = (char*)As;
    char* BsB = (char*)Bs;
    const int fr = lane & 15, k0 = (lane >> 4) * 8;

    for (int kt = 0; kt < K; kt += 32) {
        gload16(Ag0 + kt, AsB + ci0 * 1024);
        gload16(Ag1 + kt, AsB + ci1 * 1024);
        gload16(Bg0 + kt, BsB + ci0 * 1024);
        gload16(Bg1 + kt, BsB + ci1 * 1024);
        __syncthreads();
        bf16v8 a[4], b[4];
        #pragma unroll
        for (int mi = 0; mi < 4; ++mi)
            a[mi] = *(const bf16v8*)(AsB + ((wm + mi * 16 + fr) * 32 + k0) * 2);
        #pragma unroll
        for (int ni = 0; ni < 4; ++ni)
            b[ni] = *(const bf16v8*)(BsB + ((wn + ni * 16 + fr) * 32 + k0) * 2);
        #pragma unroll
        for (int mi = 0; mi < 4; ++mi)
            #pragma unroll
            for (int ni = 0; ni < 4; ++ni)
                acc[mi][ni] = __builtin_amdgcn_mfma_f32_16x16x32_bf16(a[mi], b[ni], acc[mi][ni], 0, 0, 0);
        __syncthreads();
    }
    #pragma unroll
    for (int ni = 0; ni < 4; ++ni) {
        const int n = n0 + wn + ni * 16 + fr;
        const float bv = bias ? bias[n] : 0.f;
        #pragma unroll
        for (int mi = 0; mi < 4; ++mi) {
            #pragma unroll
            for (int r = 0; r < 4; ++r) {
                const int m = m0 + wm + mi * 16 + (lane >> 4) * 4 + r;
                const float v = acc[mi][ni][r] + bv;
                if (SPLIT) {
                    if (n < 256) C[(size_t)m * 256 + n] = v;
                    else         C2[(size_t)m * 256 + (n - 256)] = v;
                } else {
                    C[(size_t)m * ldC + n] = v;
                }
            }
        }
    }
}

// ---------- recurrence MFMA GEMM with fused epilogues ----------
// M=128 (whole batch, one m-tile). EPI=0: qz head (interleaved mu/sig cols),
// EPI=1: lstm gates (interleaved i,f,g,o cols).
template<int EPI, bool INIT>
__global__ __launch_bounds__(256, 2) void rec_gemm(
    const __hip_bfloat16* __restrict__ A, int ldA,
    const __hip_bfloat16* __restrict__ B, int K,
    const float* __restrict__ bias,
    const float* __restrict__ Qe_t, const float* __restrict__ noise_t,
    float* __restrict__ qmu_out, float* __restrict__ qsig_out,
    __hip_bfloat16* __restrict__ z_out,
    const float* __restrict__ Ge_t,
    const float* __restrict__ cin, float* __restrict__ cout,
    __hip_bfloat16* __restrict__ h_out)
{
    __shared__ __hip_bfloat16 As[128 * 32];
    __shared__ __hip_bfloat16 Bs[128 * 32];
    const int n0 = blockIdx.x * 128;
    const int tid = threadIdx.x, lane = tid & 63, wave = tid >> 6;
    const int wm = (wave & 1) * 64, wn = (wave >> 1) * 64;
    f32x4 acc[4][4] = {};

    const int ci0 = wave, ci1 = wave + 4;
    const int srow0 = ci0 * 16 + (lane >> 2);
    const int srow1 = ci1 * 16 + (lane >> 2);
    const int scol = (lane & 3) * 8;
    const __hip_bfloat16* Ag0 = A + (size_t)srow0 * ldA + scol;
    const __hip_bfloat16* Ag1 = A + (size_t)srow1 * ldA + scol;
    const __hip_bfloat16* Bg0 = B + (size_t)(n0 + srow0) * K + scol;
    const __hip_bfloat16* Bg1 = B + (size_t)(n0 + srow1) * K + scol;
    char* AsB = (char*)As;
    char* BsB = (char*)Bs;
    const int fr = lane & 15, k0 = (lane >> 4) * 8;

    for (int kt = 0; kt < K; kt += 32) {
        gload16(Ag0 + kt, AsB + ci0 * 1024);
        gload16(Ag1 + kt, AsB + ci1 * 1024);
        gload16(Bg0 + kt, BsB + ci0 * 1024);
        gload16(Bg1 + kt, BsB + ci1 * 1024);
        __syncthreads();
        bf16v8 a[4], b[4];
        #pragma unroll
        for (int mi = 0; mi < 4; ++mi)
            a[mi] = *(const bf16v8*)(AsB + ((wm + mi * 16 + fr) * 32 + k0) * 2);
        #pragma unroll
        for (int ni = 0; ni < 4; ++ni)
            b[ni] = *(const bf16v8*)(BsB + ((wn + ni * 16 + fr) * 32 + k0) * 2);
        #pragma unroll
        for (int mi = 0; mi < 4; ++mi)
            #pragma unroll
            for (int ni = 0; ni < 4; ++ni)
                acc[mi][ni] = __builtin_amdgcn_mfma_f32_16x16x32_bf16(a[mi], b[ni], acc[mi][ni], 0, 0, 0);
        __syncthreads();
    }

    const int rbase = (lane >> 4) * 4;
    if constexpr (EPI == 0) {
        // cols interleaved: n=2j+s (s=0 mu, s=1 sigma). q = acc + Qe_t (bias in Qe).
        #pragma unroll
        for (int ni = 0; ni < 4; ++ni) {
            const int n = n0 + wn + ni * 16 + fr;
            const int j = n >> 1;
            #pragma unroll
            for (int mi = 0; mi < 4; ++mi) {
                #pragma unroll
                for (int r = 0; r < 4; ++r) {
                    const int m = wm + mi * 16 + rbase + r;
                    float v = acc[mi][ni][r] + Qe_t[(size_t)m * 512 + n];
                    float o = __shfl_xor(v, 1);
                    if ((n & 1) == 0) {
                        // v = q_mu, o = q_sigma
                        float z = fmaf(noise_t[(size_t)m * 8192 + j], o, v);
                        qmu_out[(size_t)m * 256 + j] = v;
                        z_out[(size_t)m * 768 + j] = __float2bfloat16(z);
                    } else {
                        qsig_out[(size_t)m * 256 + j] = v;
                    }
                }
            }
        }
    } else {
        // cols interleaved: n=4j+g, gate order i,f,g,o. Ge_t includes emb part + biases.
        #pragma unroll
        for (int ni = 0; ni < 4; ++ni) {
            const int n = n0 + wn + ni * 16 + fr;
            const int j = n >> 2, g = n & 3;
            const float bv = INIT ? bias[n] : 0.f;
            #pragma unroll
            for (int mi = 0; mi < 4; ++mi) {
                #pragma unroll
                for (int r = 0; r < 4; ++r) {
                    const int m = wm + mi * 16 + rbase + r;
                    float v = acc[mi][ni][r] + bv;
                    if constexpr (!INIT) v += Ge_t[(size_t)m * 2048 + n];
                    float x1 = __shfl_xor(v, 1);
                    float x2 = __shfl_xor(v, 2);
                    float x3 = __shfl_xor(v, 3);
                    if (g == 0) {
                        float si = sigm(v), sf = sigm(x1);
                        float tg = tanhf(x2), so = sigm(x3);
                        float cold = INIT ? 0.f : cin[(size_t)m * 512 + j];
                        float cn = fmaf(sf, cold, si * tg);
                        float hn = so * tanhf(cn);
                        cout[(size_t)m * 512 + j] = cn;
                        h_out[(size_t)m * 768 + j] = __float2bfloat16(hn);
                    }
                }
            }
        }
    }
}

// ---------- prep kernels ----------
__global__ void prep_lstm_k(const float* __restrict__ W_ih, const float* __restrict__ W_hh,
                            const float* __restrict__ b_ih, const float* __restrict__ b_hh,
                            __hip_bfloat16* __restrict__ wihE, __hip_bfloat16* __restrict__ wcat,
                            float* __restrict__ bias_comb) {
    const int r = blockIdx.x;          // dest row 0..2047, interleaved
    const int j = r >> 2, g = r & 3;
    const int src = g * 512 + j;
    for (int c = threadIdx.x; c < 512; c += 256) {
        wihE[(size_t)r * 512 + c] = __float2bfloat16(W_ih[(size_t)src * 768 + c]);
        wcat[(size_t)r * 768 + 256 + c] = __float2bfloat16(W_hh[(size_t)src * 512 + c]);
    }
    { int c = threadIdx.x & 255;
      if (c < 256) wcat[(size_t)r * 768 + c] = __float2bfloat16(W_ih[(size_t)src * 768 + 512 + c]); }
    if (threadIdx.x == 0) bias_comb[r] = b_ih[src] + b_hh[src];
}

__global__ void prep_qz_k(const float* __restrict__ qz_W, const float* __restrict__ qz_b,
                          __hip_bfloat16* __restrict__ qzwE, __hip_bfloat16* __restrict__ qzw2,
                          float* __restrict__ qzb_i) {
    const int r = blockIdx.x;          // dest row 0..511, interleaved (mu/sig)
    const int j = r >> 1, s = r & 1;
    const int src = s * 256 + j;
    for (int c = threadIdx.x; c < 512; c += 256) {
        qzwE[(size_t)r * 512 + c] = __float2bfloat16(qz_W[(size_t)src * 1024 + c]);
        qzw2[(size_t)r * 512 + c] = __float2bfloat16(qz_W[(size_t)src * 1024 + 512 + c]);
    }
    if (threadIdx.x == 0) qzb_i[r] = qz_b[src];
}

__global__ void embed_k(const float* __restrict__ embW, const int* __restrict__ cap,
                        __hip_bfloat16* __restrict__ Emb) {
    const int row = blockIdx.x;  // t*128 + b
    const int t = row >> 7, b = row & 127;
    const int tok = cap[b * 32 + t];
    const float* src = embW + (size_t)tok * 512;
    __hip_bfloat16* dst = Emb + (size_t)row * 512;
    for (int k = threadIdx.x; k < 512; k += blockDim.x)
        dst[k] = __float2bfloat16(src[k]);
}

__global__ void conv_lin_k(const float* __restrict__ s, __hip_bfloat16* __restrict__ d, int n) {
    for (int i = blockIdx.x * blockDim.x + threadIdx.x; i < n; i += gridDim.x * blockDim.x)
        d[i] = __float2bfloat16(s[i]);
}

// ---------- log_softmax: register-staged single pass, 1024 threads ----------
__global__ __launch_bounds__(1024) void lse_k(float* __restrict__ logits) {
    __shared__ float redm[16], reds[16];
    const int row = blockIdx.x, tid = threadIdx.x;
    float* p = logits + (size_t)row * 16000;
    const bool full = (tid < 928);  // chunk 3: 12288 + tid*4 < 16000
    float4 v[4];
    float mx = -3.4e38f;
    #pragma unroll
    for (int c = 0; c < 3; ++c) {
        v[c] = *(const float4*)(p + c * 4096 + tid * 4);
        mx = fmaxf(mx, fmaxf(fmaxf(v[c].x, v[c].y), fmaxf(v[c].z, v[c].w)));
    }
    if (full) {
        v[3] = *(const float4*)(p + 12288 + tid * 4);
        mx = fmaxf(mx, fmaxf(fmaxf(v[3].x, v[3].y), fmaxf(v[3].z, v[3].w)));
    }
    #pragma unroll
    for (int o = 32; o; o >>= 1) mx = fmaxf(mx, __shfl_xor(mx, o));
    if ((tid & 63) == 0) redm[tid >> 6] = mx;
    __syncthreads();
    #pragma unroll
    for (int i = 0; i < 16; ++i) mx = fmaxf(mx, redm[i]);
    float s = 0.f;
    #pragma unroll
    for (int c = 0; c < 3; ++c)
        s += __expf(v[c].x - mx) + __expf(v[c].y - mx) + __expf(v[c].z - mx) + __expf(v[c].w - mx);
    if (full)
        s += __expf(v[3].x - mx) + __expf(v[3].y - mx) + __expf(v[3].z - mx) + __expf(v[3].w - mx);
    #pragma unroll
    for (int o = 32; o; o >>= 1) s += __shfl_xor(s, o);
    if ((tid & 63) == 0) reds[tid >> 6] = s;
    __syncthreads();
    float tot = 0.f;
    #pragma unroll
    for (int i = 0; i < 16; ++i) tot += reds[i];
    const float lse = mx + logf(tot);
    #pragma unroll
    for (int c = 0; c < 3; ++c) {
        float4 w = v[c];
        w.x -= lse; w.y -= lse; w.z -= lse; w.w -= lse;
        *(float4*)(p + c * 4096 + tid * 4) = w;
    }
    if (full) {
        float4 w = v[3];
        w.x -= lse; w.y -= lse; w.z -= lse; w.w -= lse;
        *(float4*)(p + 12288 + tid * 4) = w;
    }
}

// ---------- launch ----------
extern "C" void kernel_launch(void* const* d_in, const int* in_sizes, int n_in,
                              void* d_out, int out_size, void* d_ws, size_t ws_size,
                              hipStream_t stream) {
    const float* features = (const float*)d_in[0];
    const int*   captions = (const int*)d_in[1];
    const float* noise    = (const float*)d_in[3];
    const float* embed_W  = (const float*)d_in[4];
    const float* W_ih     = (const float*)d_in[5];
    const float* W_hh     = (const float*)d_in[6];
    const float* b_ih     = (const float*)d_in[7];
    const float* b_hh     = (const float*)d_in[8];
    const float* qz_W     = (const float*)d_in[9];
    const float* qz_b     = (const float*)d_in[10];
    const float* prior_W  = (const float*)d_in[11];
    const float* prior_b  = (const float*)d_in[12];
    const float* qx_W     = (const float*)d_in[13];
    const float* qx_b     = (const float*)d_in[14];

    float* out0 = (float*)d_out;             // p_mus
    float* out1 = out0 + 4096 * 256;         // p_sigmas
    float* out2 = out1 + 4096 * 256;         // q_mus
    float* out3 = out2 + 4096 * 256;         // q_sigmas
    float* out4 = out3 + 4096 * 256;         // q_xs [4096][16000]

    char* ws = (char*)d_ws;
    __hip_bfloat16* qxWb   = (__hip_bfloat16*)(ws + 0);          // 16000x768
    __hip_bfloat16* Emb    = (__hip_bfloat16*)(ws + 24576000);   // 4096x512
    __hip_bfloat16* wihE   = (__hip_bfloat16*)(ws + 28770304);   // 2048x512 (gate-interleaved)
    __hip_bfloat16* wcat   = (__hip_bfloat16*)(ws + 30867456);   // 2048x768 [Wih2|Whh]
    __hip_bfloat16* qzwE   = (__hip_bfloat16*)(ws + 34013184);   // 512x512 (mu/sig interleaved)
    __hip_bfloat16* qzw2   = (__hip_bfloat16*)(ws + 34537472);   // 512x512
    __hip_bfloat16* priWb  = (__hip_bfloat16*)(ws + 35061760);   // 512x512
    __hip_bfloat16* featb  = (__hip_bfloat16*)(ws + 35586048);   // 128x512
    __hip_bfloat16* XH     = (__hip_bfloat16*)(ws + 35717120);   // 33 slots x 128x768 [z|h]
    float* qzb_i     = (float*)(ws + 42205184);  // 512
    float* bias_comb = (float*)(ws + 42207232);  // 2048
    float* cb0       = (float*)(ws + 42215424);  // 128x512
    float* cb1       = (float*)(ws + 42477568);  // 128x512
    float* Qe        = (float*)(ws + 42739712);  // 4096x512 f32 (ends 51.1MB)
    float* Ge        = out4;                     // 4096x2048 f32 scratch, overwritten by qx later

    // prep (independent, cheap)
    conv_lin_k<<<2048, 256, 0, stream>>>(qx_W, qxWb, 16000 * 768);
    conv_lin_k<<<256, 256, 0, stream>>>(prior_W, priWb, 512 * 512);
    conv_lin_k<<<64, 256, 0, stream>>>(features, featb, 128 * 512);
    prep_lstm_k<<<2048, 256, 0, stream>>>(W_ih, W_hh, b_ih, b_hh, wihE, wcat, bias_comb);
    prep_qz_k<<<512, 256, 0, stream>>>(qz_W, qz_b, qzwE, qzw2, qzb_i);
    embed_k<<<4096, 256, 0, stream>>>(embed_W, captions, Emb);

    // Ge = Emb @ wihE^T + bias_comb   [4096 x 2048] (gate-interleaved, bias folded)
    gemm_bt<0><<<512, 256, 0, stream>>>(Emb, 512, wihE, 512, Ge, 2048, nullptr, bias_comb, 512, 16, 1 << 30);
    // Qe = Emb @ qzwE^T + qzb_i       [4096 x 512] (mu/sig interleaved, bias folded)
    gemm_bt<0><<<128, 256, 0, stream>>>(Emb, 512, qzwE, 512, Qe, 512, nullptr, qzb_i, 512, 4, 1 << 30);

    // initial LSTM step: gates0 = featb @ wihE^T + bias_comb, c_old = 0 -> h_0, c_0
    rec_gemm<1, true><<<16, 256, 0, stream>>>(
        featb, 512, wihE, 512, bias_comb,
        nullptr, nullptr, nullptr, nullptr, nullptr,
        nullptr, nullptr, cb0, XH + 256);

    for (int t = 0; t < 32; ++t) {
        float* ccur = (t & 1) ? cb1 : cb0;
        float* cnxt = (t & 1) ? cb0 : cb1;
        __hip_bfloat16* slot = XH + (size_t)t * 98304;
        // qz head: q = h_t @ qzw2^T + Qe[t]; z = noise*sig + mu
        rec_gemm<0, false><<<4, 256, 0, stream>>>(
            slot + 256, 768, qzw2, 512, nullptr,
            Qe + (size_t)t * 128 * 512, noise + (size_t)t * 256,
            out2 + (size_t)t * 128 * 256, out3 + (size_t)t * 128 * 256, slot,
            nullptr, nullptr, nullptr, nullptr);
        // lstm: gates = [z_t|h_t] @ wcat^T + Ge[t]; update c, h
        rec_gemm<1, false><<<16, 256, 0, stream>>>(
            slot, 768, wcat, 768, nullptr,
            nullptr, nullptr, nullptr, nullptr, nullptr,
            Ge + (size_t)t * 128 * 2048, ccur, cnxt,
            XH + (size_t)(t + 1) * 98304 + 256);
    }

    // prior: P = H @ prior_W^T + prior_b -> p_mu / p_sigma
    gemm_bt<1><<<128, 256, 0, stream>>>(XH + 256, 768, priWb, 512, out0, 256, out1, prior_b, 512, 4, 1 << 30);
    // logits: [Z|H] @ qx_W^T + qx_b -> out4 (grid padded to 128 n-tiles for XCD L2 locality)
    gemm_bt<0><<<4096, 256, 0, stream>>>(XH, 768, qxWb, 768, out4, 16000, nullptr, qx_b, 768, 128, 16000);
    // in-place log_softmax
    lse_k<<<4096, 1024, 0, stream>>>(out4);
}